// Round 3
// baseline (287.308 us; speedup 1.0000x reference)
//
#include <hip/hip_runtime.h>

// SNN 2048->2048->2048->512, T=100, batch 32, LIF.
// Per layer: big GEMM over all t (M=3200=T*32) + sequential LIF scan.
// 7 stream-ordered launches, no grid sync.
//
// Unified "octet-blocked" layout (pitch MTOT) for spikes AND I:
//   half_idx(v, m) = ((v>>3)*MTOT + m)*8 + (v&7)     v = feature index
// Wave B-frag load at ((kb*4+quad)*MTOT + m0+mi)*8 yields
//   B[k=kb*32+quad*8+j][n=m0+mi]   (proven rounds 6-9).
//
// ws regions (total 39,321,600 B -- PROVEN available in round 7):
//   R0 [0,13107200) | R1 [+13107200) | I [+26214400)
// Schedule: fuse{enc->R0, convW0->R1} | gemm0(R1,R0->I) | fuse{scan0, convW1}
//   | gemm1 | fuse{scan1, convW2} | gemm2 | scan2(I->out)
//
// R12 (theory: latency-bound on restage drains + shallow B prefetch):
//   gemm64 -> counted-vmcnt quarter pipeline (T3/T4):
//   - A staged in 4 quarters of 64 KB (64 rows x 512 k), double-buffered
//     in 128 KB LDS via global_load_lds (width 16, no VGPR round-trip).
//   - boundaries use s_waitcnt vmcnt(8|4) lgkmcnt(0) + raw s_barrier +
//     sched_barrier(0): stage loads AND B prefetches stay in flight
//     across barriers (never drained to 0 mid-kernel).
//     Proof: stage(q+1) is older than all 32|16 B-reloads of quarter q;
//     <=8|4 B-loads in flight at boundary -> vmcnt(8|4) implies stage done.
//   - B prefetch deepened to 4 kb-steps via 4 NAMED reg sets b0..b3
//     (reload-after-use <- kb+4, zero copies, static indexing).
//   - stage(q+2)->buf[q&1] issued only after the boundary that ends all
//     reads of buf[q&1] (WAR-safe via lgkmcnt(0)+barrier).
#define T_STEPS 100
#define MTOT    3200
#define R0_OFF  0
#define R1_OFF  13107200
#define I_OFF   26214400

typedef _Float16 half8_t __attribute__((ext_vector_type(8)));
typedef _Float16 half4_t __attribute__((ext_vector_type(4)));
typedef float    f32x4   __attribute__((ext_vector_type(4)));

// ---------------- encode (device fn): Poisson spikes for all t ----------
__device__ __forceinline__ void encode_body(
    int blk, const float* __restrict__ x, const float* __restrict__ noise,
    _Float16* __restrict__ spk0, float* __restrict__ out)
{
    if (blk == 0 && threadIdx.x == 0) out[16384] = 0.0f;  // runs first
    const int tid = threadIdx.x;
    const int m0  = blk * 16;
    __shared__ half8_t lds[16 * 257];    // pad: store-phase reads conflict-free
    #pragma unroll
    for (int ml = 0; ml < 16; ++ml) {    // read phase: thread = feature octet
        const int m = m0 + ml;
        const int t = m >> 5, b = m & 31;
        const float4 x1 = *(const float4*)(x + b * 2048 + tid * 8);
        const float4 x2 = *(const float4*)(x + b * 2048 + tid * 8 + 4);
        const float4 n1 = *(const float4*)(noise + (size_t)t * 65536 + b * 2048 + tid * 8);
        const float4 n2 = *(const float4*)(noise + (size_t)t * 65536 + b * 2048 + tid * 8 + 4);
        const float xr[8] = {x1.x,x1.y,x1.z,x1.w,x2.x,x2.y,x2.z,x2.w};
        const float nz[8] = {n1.x,n1.y,n1.z,n1.w,n2.x,n2.y,n2.z,n2.w};
        half8_t sp;
        #pragma unroll
        for (int j = 0; j < 8; ++j) {
            const float r = fminf(fmaxf(xr[j], 0.0f), 1.0f);
            sp[j] = (nz[j] < r) ? (_Float16)1.0f : (_Float16)0.0f;
        }
        lds[ml * 257 + tid] = sp;
    }
    __syncthreads();
    #pragma unroll
    for (int r = 0; r < 16; ++r) {       // store phase: lanes = consecutive m
        const int ml  = tid & 15;
        const int oct = r * 16 + (tid >> 4);
        *(half8_t*)(spk0 + ((size_t)oct * MTOT + m0 + ml) * 8) = lds[ml * 257 + oct];
    }
}

// ------------- convw (device fn): W fp32 -> fp16 A-frag swizzled ---------
// Wf[(row>>4)*32768 + ((koct>>2)*64 + (koct&3)*16 + (row&15))*8 + j]
//   = W[row][koct*8+j];  8 rows per block.
__device__ __forceinline__ void convw_body(
    int blk, const float* __restrict__ W, _Float16* __restrict__ Wf)
{
    const int koct = threadIdx.x;        // 0..255
    #pragma unroll
    for (int r = 0; r < 8; ++r) {
        const int row = blk * 8 + r;
        const float* wp = W + (size_t)row * 2048 + koct * 8;
        const float4 f1 = *(const float4*)(wp);
        const float4 f2 = *(const float4*)(wp + 4);
        half8_t h = {(_Float16)f1.x,(_Float16)f1.y,(_Float16)f1.z,(_Float16)f1.w,
                     (_Float16)f2.x,(_Float16)f2.y,(_Float16)f2.z,(_Float16)f2.w};
        const size_t idx = (size_t)(row >> 4) * 32768
                         + ((size_t)((koct >> 2) * 64 + (koct & 3) * 16 + (row & 15))) * 8;
        *(half8_t*)(Wf + idx) = h;
    }
}

// ------------- scan (device fn): LIF, sequential t, parallel (n,b) -------
__device__ __forceinline__ void scan_body(
    int blk, const _Float16* __restrict__ I, const float* __restrict__ bias,
    _Float16* __restrict__ spk_out, float* __restrict__ out,
    const int nshift, const int is_last)
{
    const int gid = blk * 256 + threadIdx.x;     // [0, 32<<nshift)
    const int N = 1 << nshift;
    const int n = gid & (N - 1);
    const int b = gid >> nshift;
    const float bi = bias[n];
    const size_t nbase = (size_t)(n >> 3) * (MTOT * 8) + (n & 7);
    float mem = 0.f, syn = 0.f, osum = 0.f, cnt = 0.f;
    #pragma unroll 4
    for (int t = 0; t < T_STEPS; ++t) {
        const int m = t * 32 + b;
        const float Iv = (float)I[nbase + (size_t)m * 8] + bi;
        syn = syn + (-syn / 5.0f + Iv);
        mem = mem + (-mem / 20.0f + syn);
        const float sv = (mem >= 1.0f) ? 1.0f : 0.0f;
        mem = (sv != 0.0f) ? 0.0f : mem;       // reset
        mem = (mem > 0.0f) ? mem : 0.0f;       // clamp negatives
        cnt += sv; osum += sv;
        if (!is_last) spk_out[nbase + (size_t)m * 8] = (_Float16)sv;
    }
    if (is_last) out[b * 512 + n] = osum * 0.01f;    // mean over T
    float c = cnt;
    #pragma unroll
    for (int s2 = 1; s2 < 64; s2 <<= 1) c += __shfl_xor(c, s2);
    if ((threadIdx.x & 63) == 0) atomicAdd(&out[16384], c);
}

// ---------------- fused small kernels (all 256 thr) ----------------
__global__ __launch_bounds__(256, 2) void snn_enc_convw_kernel(
    const float* __restrict__ x, const float* __restrict__ noise,
    _Float16* __restrict__ spk0, float* __restrict__ out,
    const float* __restrict__ W, _Float16* __restrict__ Wf)
{
    if (blockIdx.x < 200) encode_body(blockIdx.x, x, noise, spk0, out);
    else                  convw_body(blockIdx.x - 200, W, Wf);
}

__global__ __launch_bounds__(256, 4) void snn_scan_convw_kernel(
    const _Float16* __restrict__ I, const float* __restrict__ bias,
    _Float16* __restrict__ spk_out, float* __restrict__ out,
    const int scan_blocks, const int nshift,
    const float* __restrict__ W, _Float16* __restrict__ Wf)
{
    if ((int)blockIdx.x < scan_blocks)
        scan_body(blockIdx.x, I, bias, spk_out, out, nshift, 0);
    else
        convw_body(blockIdx.x - scan_blocks, W, Wf);
}

__global__ __launch_bounds__(256, 4) void snn_scan_kernel(
    const _Float16* __restrict__ I, const float* __restrict__ bias,
    float* __restrict__ out, const int nshift)
{
    scan_body(blockIdx.x, I, bias, nullptr, out, nshift, 1);
}

// ================= 64-row GEMM (gemm0/1): I = spk @ W^T =================
// Block: 64 N-rows (4 A subtiles), 1024 thr = 16 waves, 2x64KB LDS dbuf.
// Quarter = 16 kb-steps (64 rows x 512 k = 64 KB of A). NC=8, chunk==XCD,
// jcount=25 -> 9 waves own 2 m-tiles, 7 own 1 (all 16 active).

__device__ __forceinline__ half8_t ldB(const _Float16* __restrict__ p, int kq) {
    return *(const half8_t*)(p + (size_t)kq * (MTOT * 8));
}

// Stage one 64 KB A-quarter via global_load_lds (wave-uniform dst base,
// lane-consecutive 16B). Wave w stages units [w*64, w*64+64) of each of
// the 4 row-groups (group 4nbb+r, quarter offset q*16KB).
__device__ __forceinline__ void stage_quarter(
    const _Float16* __restrict__ Wf, _Float16* __restrict__ buf,
    const int nbb, const int q, const int w, const int lane)
{
    #pragma unroll
    for (int r = 0; r < 4; ++r) {
        const _Float16* src = Wf + (size_t)(4 * nbb + r) * 32768
                            + (size_t)q * 8192 + (size_t)(w * 64 + lane) * 8;
        _Float16* dst = buf + ((size_t)r * 1024 + (size_t)w * 64) * 8;
        __builtin_amdgcn_global_load_lds(
            (const __attribute__((address_space(1))) void*)src,
            (__attribute__((address_space(3))) void*)dst, 16, 0, 0);
    }
}

// Boundary: stage(next) done (it is older than all this quarter's B
// reloads; <=8|4 B-loads in flight) WITHOUT draining the B pipeline.
template<bool HAS2>
__device__ __forceinline__ void boundary() {
    if (HAS2) asm volatile("s_waitcnt vmcnt(8) lgkmcnt(0)" ::: "memory");
    else      asm volatile("s_waitcnt vmcnt(4) lgkmcnt(0)" ::: "memory");
    __builtin_amdgcn_s_barrier();
    __builtin_amdgcn_sched_barrier(0);
}

// One k-step: 4 A ds_reads feed 4|8 MFMAs; reload this B set <- kb+4.
template<bool HAS2>
__device__ __forceinline__ void kstep(
    const _Float16* __restrict__ buf, const _Float16* const (&bp)[2],
    half8_t (&bb)[2], f32x4 (&acc)[2][4],
    const int lane, const int quad, const int kb, const int kbl)
{
    half8_t a[4];
    #pragma unroll
    for (int s = 0; s < 4; ++s)
        a[s] = *(const half8_t*)(buf + (size_t)s * 8192 + (size_t)(kbl * 64 + lane) * 8);
    #pragma unroll
    for (int s = 0; s < 4; ++s) {
        acc[0][s] = __builtin_amdgcn_mfma_f32_16x16x32_f16(a[s], bb[0], acc[0][s], 0, 0, 0);
        if (HAS2)
            acc[1][s] = __builtin_amdgcn_mfma_f32_16x16x32_f16(a[s], bb[1], acc[1][s], 0, 0, 0);
    }
    if (kb + 4 < 64) {                 // depth-4: reload for kb+4
        const int kq = (kb + 4) * 4 + quad;
        bb[0] = ldB(bp[0], kq);
        if (HAS2) bb[1] = ldB(bp[1], kq);
    }
}

template<bool HAS2, int QB>
__device__ __forceinline__ void quarter(
    const _Float16* __restrict__ buf, const _Float16* const (&bp)[2],
    half8_t (&b0)[2], half8_t (&b1)[2], half8_t (&b2)[2], half8_t (&b3)[2],
    f32x4 (&acc)[2][4], const int lane, const int quad)
{
    #pragma unroll
    for (int k4 = 0; k4 < 16; k4 += 4) {
        kstep<HAS2>(buf, bp, b0, acc, lane, quad, QB + k4 + 0, k4 + 0);
        kstep<HAS2>(buf, bp, b1, acc, lane, quad, QB + k4 + 1, k4 + 1);
        kstep<HAS2>(buf, bp, b2, acc, lane, quad, QB + k4 + 2, k4 + 2);
        kstep<HAS2>(buf, bp, b3, acc, lane, quad, QB + k4 + 3, k4 + 3);
    }
}

template<bool HAS2>
__device__ __forceinline__ void gemm64_pipe(
    const _Float16* __restrict__ Wf, _Float16 (*wlds)[32768],
    const _Float16* const (&bp)[2], const int (&mt)[2],
    const int nbb, const int row_base, const int w, const int lane,
    const int quad, const int mi, _Float16* __restrict__ I)
{
    // B preload kb 0..3 (issued FIRST -> oldest in vmcnt order).
    half8_t b0[2], b1[2], b2[2], b3[2];
    b0[0] = ldB(bp[0], quad);      b1[0] = ldB(bp[0], 4 + quad);
    b2[0] = ldB(bp[0], 8 + quad);  b3[0] = ldB(bp[0], 12 + quad);
    if (HAS2) {
        b0[1] = ldB(bp[1], quad);      b1[1] = ldB(bp[1], 4 + quad);
        b2[1] = ldB(bp[1], 8 + quad);  b3[1] = ldB(bp[1], 12 + quad);
    }
    // Stage quarters 0,1. Order: [Bpre][stage0][stage1] -> vmcnt(4)
    // waits Bpre+stage0, leaves stage1 in flight.
    stage_quarter(Wf, wlds[0], nbb, 0, w, lane);
    stage_quarter(Wf, wlds[1], nbb, 1, w, lane);
    asm volatile("s_waitcnt vmcnt(4)" ::: "memory");
    __builtin_amdgcn_s_barrier();
    __builtin_amdgcn_sched_barrier(0);

    f32x4 acc[2][4];
    #pragma unroll
    for (int u = 0; u < 2; ++u) {
        #pragma unroll
        for (int s = 0; s < 4; ++s) acc[u][s] = (f32x4){0, 0, 0, 0};
    }

    // q0 from buf0 (stage1 in flight)
    quarter<HAS2, 0>(wlds[0], bp, b0, b1, b2, b3, acc, lane, quad);
    boundary<HAS2>();
    // q1 from buf1; stage q2 -> buf0 (freed by boundary)
    stage_quarter(Wf, wlds[0], nbb, 2, w, lane);
    __builtin_amdgcn_sched_barrier(0);
    quarter<HAS2, 16>(wlds[1], bp, b0, b1, b2, b3, acc, lane, quad);
    boundary<HAS2>();
    // q2 from buf0; stage q3 -> buf1
    stage_quarter(Wf, wlds[1], nbb, 3, w, lane);
    __builtin_amdgcn_sched_barrier(0);
    quarter<HAS2, 32>(wlds[0], bp, b0, b1, b2, b3, acc, lane, quad);
    boundary<HAS2>();
    // q3 from buf1 (no more staging)
    quarter<HAS2, 48>(wlds[1], bp, b0, b1, b2, b3, acc, lane, quad);

    // store: C row(n)=quad*4+r within subtile s, col(m)=mi -> octet-blocked I
    #pragma unroll
    for (int s = 0; s < 4; ++s) {
        const int n0 = row_base + s * 16 + quad * 4;
        const size_t obase = (size_t)(n0 >> 3) * (MTOT * 8) + (n0 & 7);
        #pragma unroll
        for (int u = 0; u < 2; ++u) {
            if (u == 1 && !HAS2) continue;
            half4_t h;
            #pragma unroll
            for (int r = 0; r < 4; ++r) h[r] = (_Float16)acc[u][s][r];
            *(half4_t*)(I + obase + (size_t)(mt[u] * 16 + mi) * 8) = h;
        }
    }
}

template<int NC>
__global__ __launch_bounds__(1024, 4) void snn_gemm64_kernel(
    const _Float16* __restrict__ Wf, const _Float16* __restrict__ spk,
    _Float16* __restrict__ I)
{
    const int tid  = threadIdx.x;
    const int lane = tid & 63;
    const int w    = tid >> 6;            // wave 0..15
    const int mi   = lane & 15;
    const int quad = lane >> 4;
    const int chunk = blockIdx.x % NC;    // == XCD for NC=8
    const int nbb   = blockIdx.x / NC;    // 0..31 (64-row groups)
    const int row_base = nbb * 64;
    const int jcount = (200 - chunk + NC - 1) / NC;   // 25 for NC=8
    const int rem    = jcount - 16;       // 9: waves w<rem own 2 tiles
    const bool has2  = (w < rem);
    const int jl_start = has2 ? (2 * w) : (w + rem);  // max 24 < 25: all active

    int mt[2]; const _Float16* bp[2];
    #pragma unroll
    for (int u = 0; u < 2; ++u) {
        int jl = jl_start + u;
        if (jl >= jcount) jl = jcount - 1;            // clamp (unused slot)
        mt[u] = chunk + NC * jl;
        bp[u] = spk + ((size_t)mt[u] * 16 + mi) * 8;
    }

    __shared__ _Float16 wlds[2][32768];               // 2 x 64 KB dbuf

    if (has2) gemm64_pipe<true >(Wf, wlds, bp, mt, nbb, row_base, w, lane, quad, mi, I);
    else      gemm64_pipe<false>(Wf, wlds, bp, mt, nbb, row_base, w, lane, quad, mi, I);
}

// ============== 32-row GEMM (gemm2, proven R9 version) ==================
template<int NC, int TPW>
__global__ __launch_bounds__(1024, 4) void snn_gemm_kernel(
    const _Float16* __restrict__ Wf, const _Float16* __restrict__ spk,
    _Float16* __restrict__ I)
{
    const int tid  = threadIdx.x;
    const int lane = tid & 63;
    const int w    = tid >> 6;            // wave 0..15
    const int quad = lane >> 4, mi = lane & 15;
    const int chunk = blockIdx.x % NC;
    const int nbb   = blockIdx.x / NC;
    const int row_base = nbb * 32;
    const int jcount = (200 - chunk + NC - 1) / NC;   // 16-m-tiles in chunk

    __shared__ _Float16 wlds[32 * 2048];              // 128 KB, A-frag order
    {   // contiguous copy: Wf 16-row groups 2*nbb, 2*nbb+1
        const half8_t* __restrict__ src = (const half8_t*)(Wf + (size_t)nbb * 65536);
        half8_t* __restrict__ dst = (half8_t*)wlds;
        #pragma unroll
        for (int r = 0; r < 8; ++r) dst[tid + r * 1024] = src[tid + r * 1024];
    }
    __syncthreads();

    for (int jl0 = TPW * w; jl0 < jcount; jl0 += 16 * TPW) {
        int mt[TPW]; bool val[TPW];
        const _Float16* bp[TPW];
        #pragma unroll
        for (int u = 0; u < TPW; ++u) {
            const int jl = jl0 + u;
            val[u] = jl < jcount;
            mt[u]  = chunk + NC * (val[u] ? jl : jl0);
            bp[u]  = spk + ((size_t)mt[u] * 16 + mi) * 8;
        }
        f32x4 acc[TPW][2];
        #pragma unroll
        for (int u = 0; u < TPW; ++u) { acc[u][0] = (f32x4){0,0,0,0}; acc[u][1] = (f32x4){0,0,0,0}; }

        half8_t bc[TPW];
        const size_t k0 = (size_t)quad * (MTOT * 8);
        #pragma unroll
        for (int u = 0; u < TPW; ++u) bc[u] = *(const half8_t*)(bp[u] + k0);

        #pragma unroll 4
        for (int kb = 0; kb < 64; ++kb) {
            half8_t bn[TPW];
            if (kb < 63) {
                const size_t kn = (size_t)((kb + 1) * 4 + quad) * (MTOT * 8);
                #pragma unroll
                for (int u = 0; u < TPW; ++u) bn[u] = *(const half8_t*)(bp[u] + kn);
            }
            const half8_t a0 = *(const half8_t*)(wlds + ((size_t)(kb * 64 + lane)) * 8);
            const half8_t a1 = *(const half8_t*)(wlds + 32768 + ((size_t)(kb * 64 + lane)) * 8);
            #pragma unroll
            for (int u = 0; u < TPW; ++u) {
                acc[u][0] = __builtin_amdgcn_mfma_f32_16x16x32_f16(a0, bc[u], acc[u][0], 0, 0, 0);
                acc[u][1] = __builtin_amdgcn_mfma_f32_16x16x32_f16(a1, bc[u], acc[u][1], 0, 0, 0);
            }
            #pragma unroll
            for (int u = 0; u < TPW; ++u) bc[u] = bn[u];
        }
        // store: C row(n)=quad*4+r, col(m)=mi -> octet-blocked I
        #pragma unroll
        for (int s = 0; s < 2; ++s) {
            const int n0 = row_base + s * 16 + quad * 4;
            const size_t obase = (size_t)(n0 >> 3) * (MTOT * 8) + (n0 & 7);
            #pragma unroll
            for (int u = 0; u < TPW; ++u) {
                if (!val[u]) continue;
                half4_t h;
                #pragma unroll
                for (int r = 0; r < 4; ++r) h[r] = (_Float16)acc[u][s][r];
                *(half4_t*)(I + obase + (size_t)(mt[u] * 16 + mi) * 8) = h;
            }
        }
    }
}

extern "C" void kernel_launch(void* const* d_in, const int* in_sizes, int n_in,
                              void* d_out, int out_size, void* d_ws, size_t ws_size,
                              hipStream_t stream) {
    // setup_inputs() dict order: x, noise, time_steps, W0, b0, W1, b1, W2, b2
    const float* x     = (const float*)d_in[0];
    const float* noise = (const float*)d_in[1];
    const float* W0 = (const float*)d_in[3];
    const float* b0 = (const float*)d_in[4];
    const float* W1 = (const float*)d_in[5];
    const float* b1 = (const float*)d_in[6];
    const float* W2 = (const float*)d_in[7];
    const float* b2 = (const float*)d_in[8];
    float* out = (float*)d_out;

    _Float16* R0 = (_Float16*)((char*)d_ws + R0_OFF);
    _Float16* R1 = (_Float16*)((char*)d_ws + R1_OFF);
    _Float16* Ib = (_Float16*)((char*)d_ws + I_OFF);

    // encode -> R0 ; convW0 -> R1
    snn_enc_convw_kernel<<<dim3(456), dim3(256), 0, stream>>>(x, noise, R0, out, W0, R1);
    // gemm0: 32 nbb x 8 chunks = 256 blocks (64-row, quarter pipeline)
    snn_gemm64_kernel<8><<<dim3(256), dim3(1024), 0, stream>>>(R1, R0, Ib);
    // scan0 (I->R1, 256 blocks) ; convW1 -> R0 (256 blocks)
    snn_scan_convw_kernel<<<dim3(512), dim3(256), 0, stream>>>(Ib, b0, R1, out, 256, 11, W1, R0);
    // gemm1
    snn_gemm64_kernel<8><<<dim3(256), dim3(1024), 0, stream>>>(R0, R1, Ib);
    // scan1 (I->R0, 256 blocks) ; convW2 -> R1 (64 blocks)
    snn_scan_convw_kernel<<<dim3(320), dim3(256), 0, stream>>>(Ib, b1, R0, out, 256, 11, W2, R1);
    // gemm2: 16 nbb x 16 chunks = 256 blocks, 1 tile/wave (32-row, R9)
    snn_gemm_kernel<16, 1><<<dim3(256), dim3(1024), 0, stream>>>(R1, R0, Ib);
    // scan2 -> out
    snn_scan_kernel<<<dim3(64), dim3(256), 0, stream>>>(Ib, b2, out, 9);

    (void)in_sizes; (void)n_in; (void)out_size; (void)ws_size;
}